// Round 1
// 613.264 us; speedup vs baseline: 1.2539x; 1.2539x over previous
//
#include <hip/hip_runtime.h>
#include <cmath>

typedef __bf16 bf16;
typedef __bf16 bf16x8 __attribute__((ext_vector_type(8)));
typedef float floatx4 __attribute__((ext_vector_type(4)));

#define E_ 8
#define M_ 2048
#define D_ 1024
#define F_ 4096

#define PUNROLL _Pragma("unroll")

__device__ __forceinline__ void async16(const void* g, void* l) {
    __builtin_amdgcn_global_load_lds((const __attribute__((address_space(1))) unsigned int*)g,
                                     (__attribute__((address_space(3))) unsigned int*)l, 16, 0, 0);
}

// tanh-approx GELU: x * sigmoid(1.59577x + 0.0713548x^3). Max dev from exact ~3e-3.
__device__ __forceinline__ float gelu_fast(float u) {
    float s = u * (-1.5957691216f - 0.0713548162726f * u * u);
    return u * __builtin_amdgcn_rcpf(1.0f + __expf(s));
}

// ---- fp32 [R,C] -> bf16 transposed [C,R] tile body (64x64), verified in prior session ----
__device__ __forceinline__ void tconv_body(const float* __restrict__ in, bf16* __restrict__ out,
                                           int R, int C, int bx, int by, int bz,
                                           float (*t)[65]) {
    size_t eoff = (size_t)bz * R * C;
    in += eoff;
    out += eoff;
    const int c0 = bx * 64, r0 = by * 64;
    const int tid = threadIdx.x;
    const int f4c = tid & 15;
    const int rsub = tid >> 4;
    PUNROLL
    for (int p = 0; p < 4; ++p) {
        int row = rsub + p * 16;
        float4 v = *(const float4*)&in[(size_t)(r0 + row) * C + c0 + f4c * 4];
        t[row][f4c * 4 + 0] = v.x;
        t[row][f4c * 4 + 1] = v.y;
        t[row][f4c * 4 + 2] = v.z;
        t[row][f4c * 4 + 3] = v.w;
    }
    __syncthreads();
    const int rr = (tid & 7) * 8;
    const int cbase = tid >> 3;
    PUNROLL
    for (int p = 0; p < 2; ++p) {
        int c = cbase + p * 32;
        bf16x8 o = {(bf16)t[rr + 0][c], (bf16)t[rr + 1][c], (bf16)t[rr + 2][c],
                    (bf16)t[rr + 3][c], (bf16)t[rr + 4][c], (bf16)t[rr + 5][c],
                    (bf16)t[rr + 6][c], (bf16)t[rr + 7][c]};
        *(bf16x8*)&out[(size_t)(c0 + c) * R + r0 + rr] = o;
    }
}

// ---- fused prep: blocks [0,2048) convert x fp32->bf16; blocks [2048,10240) transpose c_fc ----
__global__ __launch_bounds__(256) void prep_kernel(const float4* __restrict__ x,
                                                   bf16x8* __restrict__ xb,
                                                   const float* __restrict__ c_fc,
                                                   bf16* __restrict__ w1T) {
    __shared__ float t[64][65];
    const int b = blockIdx.x;
    if (b < 2048) {
        const int n8 = E_ * M_ * D_ / 8;
        int i = b * 256 + threadIdx.x;
        for (; i < n8; i += 2048 * 256) {
            float4 a = x[2 * i], c = x[2 * i + 1];
            bf16x8 r = {(bf16)a.x, (bf16)a.y, (bf16)a.z, (bf16)a.w,
                        (bf16)c.x, (bf16)c.y, (bf16)c.z, (bf16)c.w};
            xb[i] = r;
        }
    } else {
        const int idx = b - 2048;  // C=F_: 64 x-tiles, R=D_: 16 y-tiles, 8 experts
        tconv_body(c_fc, w1T, D_, F_, idx & 63, (idx >> 6) & 15, idx >> 10, t);
    }
}

__global__ __launch_bounds__(256) void tconv2_kernel(const float* __restrict__ in,
                                                     bf16* __restrict__ out) {
    __shared__ float t[64][65];
    const int idx = blockIdx.x;  // C=D_: 16 x-tiles, R=F_: 64 y-tiles, 8 experts
    tconv_body(in, out, F_, D_, idx & 15, (idx >> 4) & 63, idx >> 10, t);
}

// ======================= 256x256 8-phase bf16 GEMM (B supplied transposed [N,K]) ==============
// Plain-HIP port of the m201/m248 template: BK=64, 8 waves (2M x 4N), per-wave 128x64 output.
// LDS 128KB = 2 dbuf x (A 256x64 + B 256x64) bf16; each stored as 2 halves of 128x64 (16KB).
//
// Wave row/col ownership is INTERLEAVED so each LDS half has a narrow read window:
//   wave (wm,wn): rows {wm*64..+63} u {128+wm*64..+63}, cols {wn*32..+31} u {128+wn*32..+31}.
// Per K-tile, 4 phases = C-quadrants: ph0 (mlo,nlo) reads A-lo(8xb128)+B-lo(4), ph1 (mlo,nhi)
// reads B-hi(4), ph2 (mhi,nhi) reads A-hi(8), ph3 (mhi,nlo) reads nothing (regs kept).
// => last LDS read of: A-lo @ph0, B-lo @ph0, B-hi @ph1, A-hi @ph2.
// Stage issue slots (1 half-tile = 2 global_load_lds per phase, 7 phases ahead of need):
//   ph0: (t+1).A-hi -> other buf (last read t-1.ph2, >=1 barrier before issue)   OK
//   ph1: (t+2).A-lo -> this buf  (last read t.ph0)                               OK
//   ph2: (t+2).B-lo -> this buf  (last read t.ph0)                               OK
//   ph3: (t+2).B-hi -> this buf  (last read t.ph1)                               OK
// vmcnt(6) at ph3 only (T4): 3 newest half-tiles (6 loads) may stay in flight = (t+2).{Alo,Blo,
// Bhi}; everything through (t+1).A-hi drained => tile t+1 fully resident after the ph3 barrier.
// T2 swizzle: linear LDS dest (global_load_lds requirement), per-lane global source pre-permuted
// k ^= ((row&7)<<4); ds_read applies the same XOR => uniform 8-slot bank spread.
template <bool GELU>
__global__ __launch_bounds__(512, 2) void gemm256(const bf16* __restrict__ A,
                                                  const bf16* __restrict__ Bt,
                                                  const float* __restrict__ bias,
                                                  void* __restrict__ Out,
                                                  int M, int N, int K) {
    extern __shared__ __align__(16) char sm[];
    const int nt = K >> 6;   // K-tiles of 64
    const int NTm = M >> 8;
    const int NTn = N >> 8;
    const int nwg = gridDim.x;
    const int bid = blockIdx.x;
    // T1: bijective XCD swizzle (nwg % 8 == 0 for both GEMMs), tm fastest within chunk.
    const int swz = (bid & 7) * (nwg >> 3) + (bid >> 3);
    const int tm = swz % NTm;
    const int tn = (swz / NTm) % NTn;
    const int e = swz / (NTm * NTn);
    A += (size_t)e * M * K;
    Bt += (size_t)e * N * K;
    bias += (size_t)e * N;
    const int row0 = tm << 8;
    const int col0 = tn << 8;

    const int tid = threadIdx.x;
    const int l = tid & 63;
    const int w = tid >> 6;
    const int wm = w >> 2;   // 0..1
    const int wn = w & 3;    // 0..3

    // ---- staging addresses (per-lane pre-swizzled global source) ----
    const size_t Kb = (size_t)K * 2;       // row stride in bytes
    const size_t half128 = 128 * Kb;       // +128 rows
    const size_t j64 = 64 * Kb;            // +64 rows (second issue of a half-tile)
    const int srow = (w << 3) + (l >> 3);  // 0..63
    const int kb = ((l & 7) ^ ((l >> 3) & 7)) << 4;
    const char* aSrc = (const char*)A + (size_t)(row0 + srow) * Kb + kb;
    const char* bSrc = (const char*)Bt + (size_t)(col0 + srow) * Kb + kb;
    const int ldsW = w << 10;  // wave-uniform LDS chunk base

    auto stage = [&](int hb, const char* src, int ko) {
        async16(src + ko, sm + hb + ldsW);
        async16(src + j64 + ko, sm + hb + 8192 + ldsW);
    };

    // ---- ds_read fragment addressing (XOR-swizzled) ----
    const int kpat0 = (((l >> 4) << 4)) ^ ((l & 7) << 4);       // kk=0
    const int kpat1 = (64 + ((l >> 4) << 4)) ^ ((l & 7) << 4);  // kk=1
    const int aRowOff = (((wm << 6) + (l & 15)) << 7);          // row*128B within A half
    const int bRowOff = (((wn << 5) + (l & 15)) << 7);          // col*128B within B half

    bf16x8 aa[4][2];            // current A quadrant (4 m-frags x 2 k)
    bf16x8 bb0[2][2], bb1[2][2];  // B n-lo / n-hi quadrants (kept across the K-tile)
    floatx4 acc00[4][2] = {}, acc01[4][2] = {}, acc10[4][2] = {}, acc11[4][2] = {};

#define READ_A(QM)                                                                          \
    PUNROLL                                                                                 \
    for (int mi = 0; mi < 4; ++mi) {                                                        \
        aa[mi][0] = *(const bf16x8*)(sm + p + (QM)*16384 + aRowOff + mi * 2048 + kpat0);    \
        aa[mi][1] = *(const bf16x8*)(sm + p + (QM)*16384 + aRowOff + mi * 2048 + kpat1);    \
    }
#define READ_B(BB, QN)                                                                      \
    PUNROLL                                                                                 \
    for (int ni = 0; ni < 2; ++ni) {                                                        \
        BB[ni][0] = *(const bf16x8*)(sm + p + 32768 + (QN)*16384 + bRowOff + ni * 2048 + kpat0); \
        BB[ni][1] = *(const bf16x8*)(sm + p + 32768 + (QN)*16384 + bRowOff + ni * 2048 + kpat1); \
    }
#define MQ(ACC, BB)                                                                         \
    PUNROLL                                                                                 \
    for (int mi = 0; mi < 4; ++mi) PUNROLL for (int ni = 0; ni < 2; ++ni) {                 \
        ACC[mi][ni] = __builtin_amdgcn_mfma_f32_16x16x32_bf16(aa[mi][0], BB[ni][0], ACC[mi][ni], 0, 0, 0); \
        ACC[mi][ni] = __builtin_amdgcn_mfma_f32_16x16x32_bf16(aa[mi][1], BB[ni][1], ACC[mi][ni], 0, 0, 0); \
    }

    // ---- prologue: t0.{Alo,Blo,Bhi,Ahi}, t1.{Alo,Blo,Bhi}; drain 4 oldest halves ----
    stage(0, aSrc, 0);
    stage(32768, bSrc, 0);
    stage(49152, bSrc + half128, 0);
    stage(16384, aSrc + half128, 0);
    stage(65536 + 0, aSrc, 128);
    stage(65536 + 32768, bSrc, 128);
    stage(65536 + 49152, bSrc + half128, 128);
    asm volatile("s_waitcnt vmcnt(6)" ::: "memory");
    __builtin_amdgcn_s_barrier();

    for (int t = 0; t < nt; ++t) {
        const int p = (t & 1) << 16;   // this K-tile's buffer
        const int pn = p ^ 65536;      // next K-tile's buffer
        const int ko1 = (t + 1) << 7;
        const int ko2 = (t + 2) << 7;
        // ---- phase 0: (m-lo, n-lo) ----
        READ_A(0)
        READ_B(bb0, 0)
        if (t + 1 < nt) stage(pn + 16384, aSrc + half128, ko1);  // (t+1).A-hi
        __builtin_amdgcn_s_barrier();
        __builtin_amdgcn_s_setprio(1);
        MQ(acc00, bb0)
        __builtin_amdgcn_s_setprio(0);
        __builtin_amdgcn_s_barrier();
        // ---- phase 1: (m-lo, n-hi) ----
        READ_B(bb1, 1)
        if (t + 2 < nt) stage(p + 0, aSrc, ko2);  // (t+2).A-lo
        __builtin_amdgcn_s_barrier();
        __builtin_amdgcn_s_setprio(1);
        MQ(acc01, bb1)
        __builtin_amdgcn_s_setprio(0);
        __builtin_amdgcn_s_barrier();
        // ---- phase 2: (m-hi, n-hi) ----
        READ_A(1)
        if (t + 2 < nt) stage(p + 32768, bSrc, ko2);  // (t+2).B-lo
        __builtin_amdgcn_s_barrier();
        __builtin_amdgcn_s_setprio(1);
        MQ(acc11, bb1)
        __builtin_amdgcn_s_setprio(0);
        __builtin_amdgcn_s_barrier();
        // ---- phase 3: (m-hi, n-lo) — reuse aa + bb0; counted vmcnt once per K-tile ----
        if (t + 2 < nt) {
            stage(p + 49152, bSrc + half128, ko2);  // (t+2).B-hi
            asm volatile("s_waitcnt vmcnt(6)" ::: "memory");
        } else if (t + 1 < nt) {
            asm volatile("s_waitcnt vmcnt(0)" ::: "memory");
        }
        __builtin_amdgcn_s_barrier();
        __builtin_amdgcn_s_setprio(1);
        MQ(acc10, bb0)
        __builtin_amdgcn_s_setprio(0);
        __builtin_amdgcn_s_barrier();
    }

    // ---- epilogue: C/D layout col = lane&15, row = (lane>>4)*4 + reg ----
    const size_t outBase = (size_t)e * M * N;
#define EPI(ACC, QM, QN)                                                                    \
    PUNROLL                                                                                 \
    for (int ni = 0; ni < 2; ++ni) {                                                        \
        const int col = col0 + (QN)*128 + (wn << 5) + ni * 16 + (l & 15);                   \
        const float bv = bias[col];                                                         \
        PUNROLL                                                                             \
        for (int mi = 0; mi < 4; ++mi) {                                                    \
            const int row = row0 + (QM)*128 + (wm << 6) + mi * 16 + ((l >> 4) << 2);        \
            PUNROLL                                                                         \
            for (int r = 0; r < 4; ++r) {                                                   \
                float v = ACC[mi][ni][r] + bv;                                              \
                if (GELU)                                                                   \
                    ((bf16*)Out)[outBase + (size_t)(row + r) * N + col] = (bf16)gelu_fast(v); \
                else                                                                        \
                    ((float*)Out)[outBase + (size_t)(row + r) * N + col] = v;               \
            }                                                                               \
        }                                                                                   \
    }
    EPI(acc00, 0, 0)
    EPI(acc01, 0, 1)
    EPI(acc11, 1, 1)
    EPI(acc10, 1, 0)
#undef READ_A
#undef READ_B
#undef MQ
#undef EPI
}

extern "C" void kernel_launch(void* const* d_in, const int* in_sizes, int n_in,
                              void* d_out, int out_size, void* d_ws, size_t ws_size,
                              hipStream_t stream) {
    const float* x = (const float*)d_in[0];
    const float* c_fc = (const float*)d_in[1];
    const float* c_proj = (const float*)d_in[2];
    const float* fc_bias = (const float*)d_in[3];
    const float* proj_bias = (const float*)d_in[4];
    float* out = (float*)d_out;

    bf16* xb = (bf16*)d_ws;
    bf16* wT = xb + (size_t)E_ * M_ * D_;
    bf16* h = wT + (size_t)E_ * D_ * F_;
    size_t need = ((size_t)E_ * M_ * D_ + (size_t)E_ * D_ * F_ + (size_t)E_ * M_ * F_) * 2;
    if (ws_size < need) return;

    static bool attrDone = false;
    if (!attrDone) {
        // opt-in for 128KB dynamic LDS (no-op / harmless where not required)
        (void)hipFuncSetAttribute((const void*)&gemm256<true>,
                                  hipFuncAttributeMaxDynamicSharedMemorySize, 131072);
        (void)hipFuncSetAttribute((const void*)&gemm256<false>,
                                  hipFuncAttributeMaxDynamicSharedMemorySize, 131072);
        attrDone = true;
    }

    // prep: x->bf16 (2048 blocks) + c_fc transpose (8192 blocks)
    prep_kernel<<<10240, 256, 0, stream>>>((const float4*)x, (bf16x8*)xb, c_fc, wT);
    // GEMM1: [2048,1024] x [1024,4096]^T(stored [4096,1024]) -> h bf16, GELU
    gemm256<true><<<1024, 512, 131072, stream>>>(xb, wT, fc_bias, h, M_, F_, D_);
    // c_proj transpose [4096,1024] -> [1024,4096]
    tconv2_kernel<<<8192, 256, 0, stream>>>(c_proj, wT);
    // GEMM2: [2048,4096] x [4096,1024]^T(stored [1024,4096]) -> out fp32
    gemm256<false><<<256, 512, 131072, stream>>>(h, wT, proj_bias, out, M_, D_, F_);
}

// Round 2
// 608.225 us; speedup vs baseline: 1.2642x; 1.0083x over previous
//
#include <hip/hip_runtime.h>
#include <cmath>

typedef __bf16 bf16;
typedef __bf16 bf16x8 __attribute__((ext_vector_type(8)));
typedef float floatx4 __attribute__((ext_vector_type(4)));

#define E_ 8
#define M_ 2048
#define D_ 1024
#define F_ 4096

#define PUNROLL _Pragma("unroll")

__device__ __forceinline__ void async16(const void* g, void* l) {
    __builtin_amdgcn_global_load_lds((const __attribute__((address_space(1))) unsigned int*)g,
                                     (__attribute__((address_space(3))) unsigned int*)l, 16, 0, 0);
}

// tanh-approx GELU: x * sigmoid(1.59577x + 0.0713548x^3). Max dev from exact ~3e-3.
__device__ __forceinline__ float gelu_fast(float u) {
    float s = u * (-1.5957691216f - 0.0713548162726f * u * u);
    return u * __builtin_amdgcn_rcpf(1.0f + __expf(s));
}

// ---- fp32 [R,C] -> bf16 transposed [C,R] tile body (64x64) ----
__device__ __forceinline__ void tconv_body(const float* __restrict__ in, bf16* __restrict__ out,
                                           int R, int C, int bx, int by, int bz,
                                           float (*t)[65]) {
    size_t eoff = (size_t)bz * R * C;
    in += eoff;
    out += eoff;
    const int c0 = bx * 64, r0 = by * 64;
    const int tid = threadIdx.x;
    const int f4c = tid & 15;
    const int rsub = tid >> 4;
    PUNROLL
    for (int p = 0; p < 4; ++p) {
        int row = rsub + p * 16;
        float4 v = *(const float4*)&in[(size_t)(r0 + row) * C + c0 + f4c * 4];
        t[row][f4c * 4 + 0] = v.x;
        t[row][f4c * 4 + 1] = v.y;
        t[row][f4c * 4 + 2] = v.z;
        t[row][f4c * 4 + 3] = v.w;
    }
    __syncthreads();
    const int rr = (tid & 7) * 8;
    const int cbase = tid >> 3;
    PUNROLL
    for (int p = 0; p < 2; ++p) {
        int c = cbase + p * 32;
        bf16x8 o = {(bf16)t[rr + 0][c], (bf16)t[rr + 1][c], (bf16)t[rr + 2][c],
                    (bf16)t[rr + 3][c], (bf16)t[rr + 4][c], (bf16)t[rr + 5][c],
                    (bf16)t[rr + 6][c], (bf16)t[rr + 7][c]};
        *(bf16x8*)&out[(size_t)(c0 + c) * R + r0 + rr] = o;
    }
}

__device__ __forceinline__ void xconv_body(const float4* __restrict__ x, bf16x8* __restrict__ xb,
                                           int b, int nblk) {
    const int n8 = E_ * M_ * D_ / 8;
    int i = b * 256 + threadIdx.x;
    for (; i < n8; i += nblk * 256) {
        float4 a = x[2 * i], c = x[2 * i + 1];
        bf16x8 r = {(bf16)a.x, (bf16)a.y, (bf16)a.z, (bf16)a.w,
                    (bf16)c.x, (bf16)c.y, (bf16)c.z, (bf16)c.w};
        xb[i] = r;
    }
}

// ---- fused prep (preferred path): x convert + BOTH weight transposes in one dispatch ----
// blocks [0,2048): x fp32->bf16; [2048,10240): c_fc transpose; [10240,18432): c_proj transpose.
__global__ __launch_bounds__(256) void prep_all(const float4* __restrict__ x,
                                                bf16x8* __restrict__ xb,
                                                const float* __restrict__ c_fc,
                                                bf16* __restrict__ w1T,
                                                const float* __restrict__ c_proj,
                                                bf16* __restrict__ w2T) {
    __shared__ float t[64][65];
    const int b = blockIdx.x;
    if (b < 2048) {
        xconv_body(x, xb, b, 2048);
    } else if (b < 10240) {
        const int idx = b - 2048;  // C=F_: 64 x-tiles, R=D_: 16 y-tiles, 8 experts
        tconv_body(c_fc, w1T, D_, F_, idx & 63, (idx >> 6) & 15, idx >> 10, t);
    } else {
        const int idx = b - 10240;  // C=D_: 16 x-tiles, R=F_: 64 y-tiles, 8 experts
        tconv_body(c_proj, w2T, F_, D_, idx & 15, (idx >> 4) & 63, idx >> 10, t);
    }
}

// ---- fallback path (workspace too small for separate w1T/w2T) ----
__global__ __launch_bounds__(256) void prep_kernel(const float4* __restrict__ x,
                                                   bf16x8* __restrict__ xb,
                                                   const float* __restrict__ c_fc,
                                                   bf16* __restrict__ w1T) {
    __shared__ float t[64][65];
    const int b = blockIdx.x;
    if (b < 2048) {
        xconv_body(x, xb, b, 2048);
    } else {
        const int idx = b - 2048;
        tconv_body(c_fc, w1T, D_, F_, idx & 63, (idx >> 6) & 15, idx >> 10, t);
    }
}

__global__ __launch_bounds__(256) void tconv2_kernel(const float* __restrict__ in,
                                                     bf16* __restrict__ out) {
    __shared__ float t[64][65];
    const int idx = blockIdx.x;
    tconv_body(in, out, F_, D_, idx & 15, (idx >> 4) & 63, idx >> 10, t);
}

// ======================= 256x256 8-phase bf16 GEMM (B supplied transposed [N,K]) ==============
// m201/m248 template: BK=64, 8 waves (2M x 4N), per-wave 128x64 output, 128KB LDS dbuf.
// PERSISTENT: each block processes `tpb` consecutive tiles (tm-fastest -> same tn/e, B panel
// stays L2-hot). Next tile's prologue is issued BEFORE the current epilogue so the HBM refill
// hides under the GELU+store work (epilogue touches only registers + global).
// Stage slot/hazard schedule (per K-tile, unchanged from round 1):
//   ph0: (t+1).A-hi   ph1: (t+2).A-lo   ph2: (t+2).B-lo   ph3: (t+2).B-hi + vmcnt(6)
// vmcnt(6) keeps the 3 newest half-tiles (6 loads) in flight; everything through (t+1).A-hi
// is drained => tile t+1 fully resident after ph3's barrier. Tail: vmcnt(0) at t==nt-2.
// T2 swizzle: linear LDS dest, per-lane global source pre-permuted k ^= ((row&7)<<4);
// ds_read applies the same XOR (bank-conflict-free, verified: SQ_LDS_BANK_CONFLICT == 0).
template <bool GELU>
__global__ __launch_bounds__(512, 2) void gemm256(const bf16* __restrict__ A0,
                                                  const bf16* __restrict__ Bt0,
                                                  const float* __restrict__ bias0,
                                                  void* __restrict__ Out,
                                                  int M, int N, int K, int tpb) {
    extern __shared__ __align__(16) char sm[];
    const int nt = K >> 6;   // K-tiles of 64
    const int NTm = M >> 8;
    const int NTn = N >> 8;
    const int nwg = gridDim.x;
    const int bid = blockIdx.x;
    // T1: bijective XCD swizzle (nwg % 8 == 0), tile-id = swz*tpb + j, tm fastest.
    const int swz = (bid & 7) * (nwg >> 3) + (bid >> 3);

    const int tid = threadIdx.x;
    const int l = tid & 63;
    const int w = tid >> 6;
    const int wm = w >> 2;   // 0..1
    const int wn = w & 3;    // 0..3

    const size_t Kb = (size_t)K * 2;       // row stride in bytes
    const size_t half128 = 128 * Kb;       // +128 rows
    const size_t j64 = 64 * Kb;            // +64 rows
    const int srow = (w << 3) + (l >> 3);  // 0..63
    const int kb = ((l & 7) ^ ((l >> 3) & 7)) << 4;
    const int ldsW = w << 10;  // wave-uniform LDS chunk base

    auto stage = [&](int hb, const char* src, int ko) {
        async16(src + ko, sm + hb + ldsW);
        async16(src + j64 + ko, sm + hb + 8192 + ldsW);
    };
    auto prologue = [&](const char* aS, const char* bS) {
        stage(0, aS, 0);
        stage(32768, bS, 0);
        stage(49152, bS + half128, 0);
        stage(16384, aS + half128, 0);
        stage(65536 + 0, aS, 128);
        stage(65536 + 32768, bS, 128);
        stage(65536 + 49152, bS + half128, 128);
    };

    // ds_read fragment addressing (XOR-swizzled)
    const int kpat0 = (((l >> 4) << 4)) ^ ((l & 7) << 4);       // kk=0
    const int kpat1 = (64 + ((l >> 4) << 4)) ^ ((l & 7) << 4);  // kk=1
    const int aRowOff = (((wm << 6) + (l & 15)) << 7);
    const int bRowOff = (((wn << 5) + (l & 15)) << 7);

    // ---- decode tile 0, issue its prologue ----
    int tile = swz * tpb;
    int tm = tile % NTm, rem = tile / NTm;
    int tn = rem % NTn, e = rem / NTn;
    int row0 = tm << 8, col0 = tn << 8;
    const char* aS = (const char*)A0 + ((size_t)e * M + row0 + srow) * Kb + kb;
    const char* bS = (const char*)Bt0 + ((size_t)e * N + col0 + srow) * Kb + kb;
    prologue(aS, bS);

    for (int j = 0; j < tpb; ++j) {
        asm volatile("s_waitcnt vmcnt(6)" ::: "memory");
        __builtin_amdgcn_s_barrier();

        bf16x8 aa[4][2];
        bf16x8 bb0[2][2], bb1[2][2];
        floatx4 acc00[4][2] = {}, acc01[4][2] = {}, acc10[4][2] = {}, acc11[4][2] = {};

#define READ_A(QM)                                                                          \
    PUNROLL                                                                                 \
    for (int mi = 0; mi < 4; ++mi) {                                                        \
        aa[mi][0] = *(const bf16x8*)(sm + p + (QM)*16384 + aRowOff + mi * 2048 + kpat0);    \
        aa[mi][1] = *(const bf16x8*)(sm + p + (QM)*16384 + aRowOff + mi * 2048 + kpat1);    \
    }
#define READ_B(BB, QN)                                                                      \
    PUNROLL                                                                                 \
    for (int ni = 0; ni < 2; ++ni) {                                                        \
        BB[ni][0] = *(const bf16x8*)(sm + p + 32768 + (QN)*16384 + bRowOff + ni * 2048 + kpat0); \
        BB[ni][1] = *(const bf16x8*)(sm + p + 32768 + (QN)*16384 + bRowOff + ni * 2048 + kpat1); \
    }
#define MQ(ACC, BB)                                                                         \
    PUNROLL                                                                                 \
    for (int mi = 0; mi < 4; ++mi) PUNROLL for (int ni = 0; ni < 2; ++ni) {                 \
        ACC[mi][ni] = __builtin_amdgcn_mfma_f32_16x16x32_bf16(aa[mi][0], BB[ni][0], ACC[mi][ni], 0, 0, 0); \
        ACC[mi][ni] = __builtin_amdgcn_mfma_f32_16x16x32_bf16(aa[mi][1], BB[ni][1], ACC[mi][ni], 0, 0, 0); \
    }

        for (int t = 0; t < nt; ++t) {
            const int p = (t & 1) << 16;
            const int pn = p ^ 65536;
            const int ko1 = (t + 1) << 7;
            const int ko2 = (t + 2) << 7;
            // ---- phase 0: (m-lo, n-lo) ----
            READ_A(0)
            READ_B(bb0, 0)
            if (t + 1 < nt) stage(pn + 16384, aS + half128, ko1);  // (t+1).A-hi
            __builtin_amdgcn_s_barrier();
            __builtin_amdgcn_s_setprio(1);
            MQ(acc00, bb0)
            __builtin_amdgcn_s_setprio(0);
            __builtin_amdgcn_s_barrier();
            // ---- phase 1: (m-lo, n-hi) ----
            READ_B(bb1, 1)
            if (t + 2 < nt) stage(p + 0, aS, ko2);  // (t+2).A-lo
            __builtin_amdgcn_s_barrier();
            __builtin_amdgcn_s_setprio(1);
            MQ(acc01, bb1)
            __builtin_amdgcn_s_setprio(0);
            __builtin_amdgcn_s_barrier();
            // ---- phase 2: (m-hi, n-hi) ----
            READ_A(1)
            if (t + 2 < nt) stage(p + 32768, bS, ko2);  // (t+2).B-lo
            __builtin_amdgcn_s_barrier();
            __builtin_amdgcn_s_setprio(1);
            MQ(acc11, bb1)
            __builtin_amdgcn_s_setprio(0);
            __builtin_amdgcn_s_barrier();
            // ---- phase 3: (m-hi, n-lo) ----
            if (t + 2 < nt) {
                stage(p + 49152, bS + half128, ko2);  // (t+2).B-hi
                asm volatile("s_waitcnt vmcnt(6)" ::: "memory");
            } else if (t + 1 < nt) {
                asm volatile("s_waitcnt vmcnt(0)" ::: "memory");
            }
            __builtin_amdgcn_s_barrier();
            __builtin_amdgcn_s_setprio(1);
            MQ(acc10, bb0)
            __builtin_amdgcn_s_setprio(0);
            __builtin_amdgcn_s_barrier();
        }

        // ---- save current tile's epilogue params, then issue next tile's prologue ----
        const int erow0 = row0, ecol0 = col0;
        const float* ebias = bias0 + (size_t)e * N;
        const size_t eout = (size_t)e * M * N;
        if (j + 1 < tpb) {
            tile = swz * tpb + j + 1;
            tm = tile % NTm; rem = tile / NTm;
            tn = rem % NTn; e = rem / NTn;
            row0 = tm << 8; col0 = tn << 8;
            aS = (const char*)A0 + ((size_t)e * M + row0 + srow) * Kb + kb;
            bS = (const char*)Bt0 + ((size_t)e * N + col0 + srow) * Kb + kb;
            prologue(aS, bS);  // LDS fully free after final barrier; hides under epilogue
        }

        // ---- epilogue: C/D layout col = lane&15, row = (lane>>4)*4 + reg ----
#define EPI(ACC, QM, QN)                                                                    \
    PUNROLL                                                                                 \
    for (int ni = 0; ni < 2; ++ni) {                                                        \
        const int col = ecol0 + (QN)*128 + (wn << 5) + ni * 16 + (l & 15);                  \
        const float bv = ebias[col];                                                        \
        PUNROLL                                                                             \
        for (int mi = 0; mi < 4; ++mi) {                                                    \
            const int row = erow0 + (QM)*128 + (wm << 6) + mi * 16 + ((l >> 4) << 2);       \
            PUNROLL                                                                         \
            for (int r = 0; r < 4; ++r) {                                                   \
                float v = ACC[mi][ni][r] + bv;                                              \
                if (GELU)                                                                   \
                    ((bf16*)Out)[eout + (size_t)(row + r) * N + col] = (bf16)gelu_fast(v);  \
                else                                                                        \
                    ((float*)Out)[eout + (size_t)(row + r) * N + col] = v;                  \
            }                                                                               \
        }                                                                                   \
    }
        EPI(acc00, 0, 0)
        EPI(acc01, 0, 1)
        EPI(acc11, 1, 1)
        EPI(acc10, 1, 0)
#undef READ_A
#undef READ_B
#undef MQ
#undef EPI
    }
}

extern "C" void kernel_launch(void* const* d_in, const int* in_sizes, int n_in,
                              void* d_out, int out_size, void* d_ws, size_t ws_size,
                              hipStream_t stream) {
    const float* x = (const float*)d_in[0];
    const float* c_fc = (const float*)d_in[1];
    const float* c_proj = (const float*)d_in[2];
    const float* fc_bias = (const float*)d_in[3];
    const float* proj_bias = (const float*)d_in[4];
    float* out = (float*)d_out;

    const size_t EMD = (size_t)E_ * M_ * D_;   // 16.8M
    const size_t EDF = (size_t)E_ * D_ * F_;   // 33.6M
    const size_t EMF = (size_t)E_ * M_ * F_;   // 67.1M
    const size_t need1 = (EMD + EDF + EMF) * 2;        // shared w1T/w2T buffer (old path)
    const size_t need2 = (EMD + 2 * EDF + EMF) * 2;    // separate w1T + w2T (fused path)
    if (ws_size < need1) return;

    static bool attrDone = false;
    if (!attrDone) {
        (void)hipFuncSetAttribute((const void*)&gemm256<true>,
                                  hipFuncAttributeMaxDynamicSharedMemorySize, 131072);
        (void)hipFuncSetAttribute((const void*)&gemm256<false>,
                                  hipFuncAttributeMaxDynamicSharedMemorySize, 131072);
        attrDone = true;
    }

    bf16* xb = (bf16*)d_ws;
    bf16* w1T = xb + EMD;

    if (ws_size >= need2) {
        // fused path: all prep in ONE dispatch, both transposed weights live simultaneously
        bf16* w2T = w1T + EDF;
        bf16* h = w2T + EDF;
        prep_all<<<18432, 256, 0, stream>>>((const float4*)x, (bf16x8*)xb, c_fc, w1T,
                                            c_proj, w2T);
        gemm256<true><<<256, 512, 131072, stream>>>(xb, w1T, fc_bias, h, M_, F_, D_, 4);
        gemm256<false><<<256, 512, 131072, stream>>>(h, w2T, proj_bias, out, M_, D_, F_, 1);
    } else {
        // fallback: shared weight buffer, c_proj transpose between the GEMMs
        bf16* h = w1T + EDF;
        prep_kernel<<<10240, 256, 0, stream>>>((const float4*)x, (bf16x8*)xb, c_fc, w1T);
        gemm256<true><<<256, 512, 131072, stream>>>(xb, w1T, fc_bias, h, M_, F_, D_, 4);
        tconv2_kernel<<<8192, 256, 0, stream>>>(c_proj, w1T);
        gemm256<false><<<256, 512, 131072, stream>>>(h, w1T, proj_bias, out, M_, D_, F_, 1);
    }
}